// Round 3
// baseline (1194.772 us; speedup 1.0000x reference)
//
#include <hip/hip_runtime.h>

#define A_N   50000
#define P_N   100000
#define DIN   128
#define H_DIM 256
#define C_CLS 40
#define E_N   300000
#define EPS_LN 1e-5f

typedef short bf16x8 __attribute__((ext_vector_type(8)));
typedef float f32x4  __attribute__((ext_vector_type(4)));
typedef unsigned short u16;

__device__ __forceinline__ u16 f2bf(float x) {
    union { float f; unsigned u; } v; v.f = x;
    unsigned r = v.u + 0x7fff + ((v.u >> 16) & 1);
    return (u16)(r >> 16);
}
__device__ __forceinline__ float bf2f(u16 h) {
    union { unsigned u; float f; } v; v.u = ((unsigned)h) << 16;
    return v.f;
}

// async global->LDS, 16 B per lane; lds base must be wave-uniform (HW scatters lane*16)
__device__ __forceinline__ void gl2lds16(const u16* g, u16* ldsbase) {
    __builtin_amdgcn_global_load_lds(
        (const __attribute__((address_space(1))) unsigned int*)g,
        (__attribute__((address_space(3))) unsigned int*)ldsbase, 16, 0, 0);
}

// ================= general bf16 MFMA GEMM: C[N,M] = sum_seg A_seg[N,K] @ (BT_seg[M,K])^T ======
// 128x128 tile, BK=32, 256 threads (4 waves), wave = 64x64 via 4x4 of 16x16x32 MFMA.
// LDS [row][32] unpadded (global_load_lds layout); frag b128 reads are bank-balanced.
#define GBN 128
#define GBM 128

__launch_bounds__(256)
__global__ void gemm_mfma2(const u16* __restrict__ A0, const u16* __restrict__ A1,
                           const u16* __restrict__ A2,
                           const u16* __restrict__ B0, const u16* __restrict__ B1,
                           const u16* __restrict__ B2,
                           int nseg, const float* __restrict__ bias,
                           float* __restrict__ C32, u16* __restrict__ C16,
                           int N, int K, int M, int relu)
{
    __shared__ u16 As[GBN * 32];   // 8 KB
    __shared__ u16 Bs[GBM * 32];   // 8 KB

    const int tid  = threadIdx.x;
    const int wave = tid >> 6;
    const int lane = tid & 63;
    const int n0 = blockIdx.y * GBN;
    const int m0 = blockIdx.x * GBM;
    const int wrow = (wave >> 1) * 64;
    const int wcol = (wave & 1) * 64;
    const int lm   = lane & 15;
    const int quad = lane >> 4;
    const int rg = lane >> 2;      // staging: 4 lanes/row (64 B rows), 16 rows/instr
    const int ch = lane & 3;       // 16B chunk within row

    f32x4 acc[4][4];
    #pragma unroll
    for (int i = 0; i < 4; ++i)
        #pragma unroll
        for (int j = 0; j < 4; ++j)
            acc[i][j] = (f32x4)0.0f;

    for (int seg = 0; seg < nseg; ++seg) {
        const u16* Aseg = (seg == 0) ? A0 : (seg == 1) ? A1 : A2;
        const u16* Bseg = (seg == 0) ? B0 : (seg == 1) ? B1 : B2;

        for (int k0 = 0; k0 < K; k0 += 32) {
            __syncthreads();   // previous tile fully consumed before overwrite
            #pragma unroll
            for (int i = 0; i < 2; ++i) {
                int lr = wave * 32 + i * 16;
                int grow = n0 + lr + rg; if (grow > N - 1) grow = N - 1;
                gl2lds16(Aseg + (size_t)grow * K + k0 + ch * 8, &As[lr * 32]);
            }
            #pragma unroll
            for (int i = 0; i < 2; ++i) {
                int lr = wave * 32 + i * 16;
                int brow = m0 + lr + rg; if (brow > M - 1) brow = M - 1;
                gl2lds16(Bseg + (size_t)brow * K + k0 + ch * 8, &Bs[lr * 32]);
            }
            __syncthreads();   // vmcnt drain + barrier

            bf16x8 af[4], bfr[4];
            #pragma unroll
            for (int i = 0; i < 4; ++i)
                af[i] = *(const bf16x8*)&As[(wrow + i * 16 + lm) * 32 + quad * 8];
            #pragma unroll
            for (int j = 0; j < 4; ++j)
                bfr[j] = *(const bf16x8*)&Bs[(wcol + j * 16 + lm) * 32 + quad * 8];
            #pragma unroll
            for (int i = 0; i < 4; ++i)
                #pragma unroll
                for (int j = 0; j < 4; ++j)
                    acc[i][j] = __builtin_amdgcn_mfma_f32_16x16x32_bf16(af[i], bfr[j], acc[i][j], 0, 0, 0);
        }
    }

    // epilogue: C/D layout col=lane&15, row=quad*4+reg
    float bj[4];
    #pragma unroll
    for (int j = 0; j < 4; ++j) {
        int gcol = m0 + wcol + j * 16 + lm;
        bj[j] = (bias && gcol < M) ? bias[gcol] : 0.f;
    }
    #pragma unroll
    for (int i = 0; i < 4; ++i) {
        #pragma unroll
        for (int r = 0; r < 4; ++r) {
            int grow = n0 + wrow + i * 16 + quad * 4 + r;
            if (grow >= N) continue;
            #pragma unroll
            for (int j = 0; j < 4; ++j) {
                int gcol = m0 + wcol + j * 16 + lm;
                if (gcol >= M) continue;
                float v = acc[i][j][r] + bj[j];
                if (relu) v = fmaxf(v, 0.f);
                if (C32) C32[(size_t)grow * M + gcol] = v;
                if (C16) C16[(size_t)grow * M + gcol] = f2bf(v);
            }
        }
    }
}

// ========== fused layer GEMM + relu + residual + LayerNorm, in-place on H (bf16) ==========
// v3: 2-phase pipelined, A-in-registers.
//   - A rows are wave-private -> no LDS staging; A frags loaded global->VGPR, prefetched
//     one K-step ahead into named regs (a0n/a1n).  Per-row 4 quads are contiguous 64 B
//     -> coalesced.
//   - B double-buffered in LDS at BK=32 (Bs[2][256*32] = 32 KB total).  Per step: issue
//     next-step stage into buf^1 BEFORE computing on buf, ONE __syncthreads() per step
//     AFTER compute -> the vmcnt(0) drain lands after ~32 MFMA + 16 ds_read of cover
//     (catalog T3 minimum-2-phase).  v2's exposed-drain structure (2 barriers/step,
//     drain right after issue) was the 132 us regression.
//   - swizzle for 64 B rows: chunk c ^= (row>>1)&3 on BOTH gl2lds source and ds_read
//     offset -> per quarter-wave 16 lanes cover each bank-pair exactly 2x (free, m136).
//   - __launch_bounds__(256,3): pin 3 waves/SIMD (VGPR cap 170; acc[2][16]=128 + A regs).
// Safe in-place: block touches only its own 128 rows; writes after k-loop.
__launch_bounds__(256, 3)
__global__ void gemm_ln(const u16* __restrict__ A0, const u16* __restrict__ A1,
                        const u16* __restrict__ A2,
                        const u16* __restrict__ B0, const u16* __restrict__ B1,
                        const u16* __restrict__ B2,
                        int nseg, const float* __restrict__ bias,
                        const float* __restrict__ lng, const float* __restrict__ lnb,
                        u16* __restrict__ H, int N)
{
    __shared__ u16 Bs[2][256 * 32];   // 2 x 16 KB double buffer

    const int tid  = threadIdx.x;
    const int wave = tid >> 6;
    const int lane = tid & 63;
    const int n0 = blockIdx.x * 128;
    const int lm   = lane & 15;
    const int quad = lane >> 4;
    // B staging: 4 lanes/row (64 B rows), 16 rows/instr; wave stages rows wave*64..+63
    const int rg = lane >> 2;
    const int ch = lane & 3;
    const int csrc = ((ch ^ ((rg >> 1) & 3)) << 3);   // swizzled source chunk (u16 units)
    // B read: G[row][quad] lives at LDS chunk quad ^ ((row>>1)&3); row=j*16+lm -> lm-only
    const int xo = ((quad ^ ((lm >> 1) & 3)) << 3);

    // A rows owned by this wave (clamped); frag addr = row*H_DIM + k0 + quad*8
    int ra0 = n0 + wave * 32 + lm;      if (ra0 > N - 1) ra0 = N - 1;
    int ra1 = n0 + wave * 32 + 16 + lm; if (ra1 > N - 1) ra1 = N - 1;
    const size_t aoff0 = (size_t)ra0 * H_DIM + quad * 8;
    const size_t aoff1 = (size_t)ra1 * H_DIM + quad * 8;

    f32x4 acc[2][16];
    #pragma unroll
    for (int i = 0; i < 2; ++i)
        #pragma unroll
        for (int j = 0; j < 16; ++j) acc[i][j] = (f32x4)0.0f;

    const int T = nseg * 8;   // K-steps of 32 (K=256/seg)

    // prologue: stage B[t=0] into buf 0, load A[t=0]
    #pragma unroll
    for (int g = 0; g < 4; ++g) {
        int lr = wave * 64 + g * 16;
        gl2lds16(B0 + (size_t)(lr + rg) * H_DIM + csrc, &Bs[0][lr * 32]);
    }
    bf16x8 a0c = *(const bf16x8*)(A0 + aoff0);
    bf16x8 a1c = *(const bf16x8*)(A0 + aoff1);
    __syncthreads();   // drains vmcnt -> Bs[0] ready

    int buf = 0;
    for (int t = 0; t < T; ++t) {
        bf16x8 a0n = a0c, a1n = a1c;
        const int tn = t + 1;
        if (tn < T) {
            const int sn = tn >> 3;
            const int kn = (tn & 7) * 32;
            const u16* Bn = (sn == 0) ? B0 : (sn == 1) ? B1 : B2;
            #pragma unroll
            for (int g = 0; g < 4; ++g) {
                int lr = wave * 64 + g * 16;
                gl2lds16(Bn + (size_t)(lr + rg) * H_DIM + kn + csrc, &Bs[buf ^ 1][lr * 32]);
            }
            const u16* An = (sn == 0) ? A0 : (sn == 1) ? A1 : A2;
            a0n = *(const bf16x8*)(An + aoff0 + kn);
            a1n = *(const bf16x8*)(An + aoff1 + kn);
        }
        // compute on Bs[buf] (staged last step, drained at last step's barrier)
        const u16* bp = &Bs[buf][0];
        #pragma unroll
        for (int j = 0; j < 16; ++j) {
            bf16x8 bfr = *(const bf16x8*)&bp[(j * 16 + lm) * 32 + xo];
            acc[0][j] = __builtin_amdgcn_mfma_f32_16x16x32_bf16(a0c, bfr, acc[0][j], 0, 0, 0);
            acc[1][j] = __builtin_amdgcn_mfma_f32_16x16x32_bf16(a1c, bfr, acc[1][j], 0, 0, 0);
        }
        __syncthreads();   // single drain/step: next-stage had the whole compute to land
        buf ^= 1;
        a0c = a0n; a1c = a1n;
    }

    // epilogue: per accumulator row: relu + bias, + residual H, LN over 256 cols, write bf16
    #pragma unroll
    for (int i = 0; i < 2; ++i) {
        #pragma unroll
        for (int r = 0; r < 4; ++r) {
            int grow = n0 + wave * 32 + i * 16 + quad * 4 + r;   // uniform across the 16 lm lanes
            if (grow >= N) continue;
            float v[16];
            float ps = 0.f, pq = 0.f;
            #pragma unroll
            for (int j = 0; j < 16; ++j) {
                int col = j * 16 + lm;
                float x = fmaxf(acc[i][j][r] + bias[col], 0.f);
                x += bf2f(H[(size_t)grow * H_DIM + col]);
                v[j] = x; ps += x; pq += x * x;
            }
            #pragma unroll
            for (int off = 1; off < 16; off <<= 1) {
                ps += __shfl_xor(ps, off, 64);
                pq += __shfl_xor(pq, off, 64);
            }
            float mean = ps * (1.0f / H_DIM);
            float var  = pq * (1.0f / H_DIM) - mean * mean;
            float inv  = rsqrtf(var + EPS_LN);
            #pragma unroll
            for (int j = 0; j < 16; ++j) {
                int col = j * 16 + lm;
                H[(size_t)grow * H_DIM + col] = f2bf((v[j] - mean) * inv * lng[col] + lnb[col]);
            }
        }
    }
}

// ---------------- conversions ----------------
__global__ void xconv_kernel(const float* __restrict__ x, u16* __restrict__ o, int n4)
{
    int i = blockIdx.x * blockDim.x + threadIdx.x;
    if (i >= n4) return;
    float4 v = ((const float4*)x)[i];
    ushort4 u;
    u.x = f2bf(v.x); u.y = f2bf(v.y); u.z = f2bf(v.z); u.w = f2bf(v.w);
    ((ushort4*)o)[i] = u;
}

__global__ void wconv_kernel(const float* __restrict__ W, u16* __restrict__ WT,
                             int K, int M, int count)
{
    int idx = blockIdx.x * blockDim.x + threadIdx.x;
    int per = K * M;
    if (idx >= per * count) return;
    int b = idx / per, rem = idx - b * per;
    int k = rem / M, m = rem - k * M;
    WT[(size_t)b * per + (size_t)m * K + k] = f2bf(W[idx]);
}

__global__ void wsum_kernel(const float* __restrict__ Wself, u16* __restrict__ WT)
{
    int idx = blockIdx.x * blockDim.x + threadIdx.x;
    const int per = H_DIM * H_DIM;
    if (idx >= 2 * per) return;
    int l = idx / per, rem = idx - l * per;
    int k = rem / H_DIM, m = rem - k * H_DIM;
    float v = Wself[(size_t)(l * 3 + 0) * per + rem] + Wself[(size_t)(l * 3 + 1) * per + rem];
    WT[(size_t)l * per + (size_t)m * H_DIM + k] = f2bf(v);
}

__global__ void bsum_kernel(const float* __restrict__ bconv, float* __restrict__ bsum)
{
    int idx = blockIdx.x * blockDim.x + threadIdx.x;
    if (idx >= 2 * H_DIM) return;
    int l = idx >> 8, j = idx & 255;
    bsum[idx] = bconv[(l * 3 + 0) * H_DIM + j] + bconv[(l * 3 + 1) * H_DIM + j];
}

// ---------------- CSR build ----------------
__global__ void degi_kernel(const int* __restrict__ dst, int* __restrict__ deg, int E)
{
    int i = blockIdx.x * blockDim.x + threadIdx.x;
    if (i < E) atomicAdd(&deg[dst[i]], 1);
}

__device__ __forceinline__ int block_exscan256(int val, int* lds, int* total)
{
    int t = threadIdx.x;
    lds[t] = val;
    __syncthreads();
    #pragma unroll
    for (int off = 1; off < 256; off <<= 1) {
        int y = (t >= off) ? lds[t - off] : 0;
        __syncthreads();
        lds[t] += y;
        __syncthreads();
    }
    int inc = lds[t];
    *total = lds[255];
    __syncthreads();
    return inc - val;
}

__global__ void scan1_kernel(const int* __restrict__ in, int* __restrict__ out,
                             int* __restrict__ sums, int n)
{
    __shared__ int lds[256];
    int t = threadIdx.x;
    int base = blockIdx.x * 1024 + t * 4;
    int v0 = 0, v1 = 0, v2 = 0, v3 = 0;
    if (base + 3 < n) {
        int4 q = *(const int4*)(in + base);
        v0 = q.x; v1 = q.y; v2 = q.z; v3 = q.w;
    } else {
        if (base     < n) v0 = in[base];
        if (base + 1 < n) v1 = in[base + 1];
        if (base + 2 < n) v2 = in[base + 2];
    }
    int tot = v0 + v1 + v2 + v3, bt;
    int ex = block_exscan256(tot, lds, &bt);
    if (base     < n) out[base]     = ex;
    if (base + 1 < n) out[base + 1] = ex + v0;
    if (base + 2 < n) out[base + 2] = ex + v0 + v1;
    if (base + 3 < n) out[base + 3] = ex + v0 + v1 + v2;
    if (t == 0) sums[blockIdx.x] = bt;
}

__global__ void scan2_kernel(int* __restrict__ sums, int nc)
{
    __shared__ int lds[256];
    int t = threadIdx.x;
    int v = (t < nc) ? sums[t] : 0;
    int bt;
    int ex = block_exscan256(v, lds, &bt);
    if (t < nc) sums[t] = ex;
}

__global__ void scan3_kernel(int* __restrict__ cur, const int* __restrict__ sums, int n)
{
    int i = blockIdx.x * blockDim.x + threadIdx.x;
    if (i < n) cur[i] += sums[i >> 10];
}

__global__ void csr_fill_kernel(const int* __restrict__ src, const int* __restrict__ dst,
                                int* __restrict__ cur, int* __restrict__ csr, int E)
{
    int e = blockIdx.x * blockDim.x + threadIdx.x;
    if (e < E) {
        int pos = atomicAdd(&cur[dst[e]], 1);
        csr[pos] = src[e];
    }
}

// ---------------- pull-style mean aggregation: 2 dst rows per wave, 16 B/lane ----------------
typedef unsigned short u16x8 __attribute__((ext_vector_type(8)));

__launch_bounds__(256)
__global__ void gather_mean_kernel(const u16* __restrict__ h, const int* __restrict__ cur,
                                   const int* __restrict__ deg, const int* __restrict__ csr,
                                   u16* __restrict__ agg, int N)
{
    int gid = blockIdx.x * blockDim.x + threadIdx.x;
    int d = gid >> 5;
    if (d >= N) return;
    int l = gid & 31;               // 32 chunks of 8 bf16 per 256-wide row
    int dg = deg[d];
    int o  = cur[d] - dg;
    float a[8] = {};
    for (int i = 0; i < dg; ++i) {
        int s = csr[o + i];
        u16x8 v = *(const u16x8*)(h + (size_t)s * H_DIM + l * 8);
        #pragma unroll
        for (int t = 0; t < 8; ++t) a[t] += bf2f(v[t]);
    }
    float r = (dg > 0) ? (1.0f / (float)dg) : 0.f;
    u16x8 u;
    #pragma unroll
    for (int t = 0; t < 8; ++t) u[t] = f2bf(a[t] * r);
    *(u16x8*)(agg + (size_t)d * H_DIM + l * 8) = u;
}

// ---------------- in-place log_softmax ----------------
__launch_bounds__(256)
__global__ void logsoftmax_kernel(float* __restrict__ x, int N, int C)
{
    int gid = blockIdx.x * blockDim.x + threadIdx.x;
    int row = gid >> 6;
    if (row >= N) return;
    int lane = threadIdx.x & 63;
    float v = (lane < C) ? x[(size_t)row * C + lane] : -3.0e38f;
    float m = v;
    #pragma unroll
    for (int off = 32; off; off >>= 1) m = fmaxf(m, __shfl_xor(m, off, 64));
    float e = (lane < C) ? __expf(v - m) : 0.f;
    float s = e;
    #pragma unroll
    for (int off = 32; off; off >>= 1) s += __shfl_xor(s, off, 64);
    float ls = logf(s);
    if (lane < C) x[(size_t)row * C + lane] = v - m - ls;
}

// ======================================================================================
extern "C" void kernel_launch(void* const* d_in, const int* in_sizes, int n_in,
                              void* d_out, int out_size, void* d_ws, size_t ws_size,
                              hipStream_t stream)
{
    const float* x_author = (const float*)d_in[0];
    const float* x_paper  = (const float*)d_in[1];
    const int* e0s = (const int*)d_in[2]; const int* e0d = (const int*)d_in[3];
    const int* e1s = (const int*)d_in[4]; const int* e1d = (const int*)d_in[5];
    const int* e2s = (const int*)d_in[6]; const int* e2d = (const int*)d_in[7];
    const float* embWa = (const float*)d_in[8];  const float* embba = (const float*)d_in[9];
    const float* embWp = (const float*)d_in[10]; const float* embbp = (const float*)d_in[11];
    const float* Wself  = (const float*)d_in[12];
    const float* Wneigh = (const float*)d_in[13];
    const float* bconv  = (const float*)d_in[14];
    const float* lnga = (const float*)d_in[15]; const float* lnba = (const float*)d_in[16];
    const float* lngp = (const float*)d_in[17]; const float* lnbp = (const float*)d_in[18];
    const float* pW1a = (const float*)d_in[19]; const float* pb1a = (const float*)d_in[20];
    const float* pW2a = (const float*)d_in[21]; const float* pb2a = (const float*)d_in[22];
    const float* pW1p = (const float*)d_in[23]; const float* pb1p = (const float*)d_in[24];
    const float* pW2p = (const float*)d_in[25];

    // ---- workspace carve ----
    char* wp = (char*)d_ws;
    auto carveF = [&](size_t n) { float* p = (float*)wp; wp += n * sizeof(float); return p; };
    auto carveU = [&](size_t n) { u16* p = (u16*)wp; wp += n * sizeof(u16); return p; };
    auto carveI = [&](size_t n) { int* p = (int*)wp; wp += n * sizeof(int); return p; };

    float* BSUM = carveF(2 * H_DIM);

    u16* HA16  = carveU((size_t)A_N * H_DIM);
    u16* HP16  = carveU((size_t)P_N * H_DIM);
    u16* AGG0  = carveU((size_t)P_N * H_DIM);
    u16* AGG1  = carveU((size_t)P_N * H_DIM);
    u16* AGGA  = carveU((size_t)A_N * H_DIM);
    u16* XA16  = carveU((size_t)A_N * DIN);
    u16* XP16  = carveU((size_t)P_N * DIN);
    u16* WsT    = carveU(6 * H_DIM * H_DIM);
    u16* WnT    = carveU(6 * H_DIM * H_DIM);
    u16* WsumT  = carveU(2 * H_DIM * H_DIM);
    u16* embWaT = carveU(DIN * H_DIM);
    u16* embWpT = carveU(DIN * H_DIM);
    u16* pW1aT  = carveU(H_DIM * H_DIM);
    u16* pW2aT  = carveU(H_DIM * C_CLS);
    u16* pW1pT  = carveU(H_DIM * H_DIM);
    u16* pW2pT  = carveU(H_DIM * H_DIM);

    int* ideg = carveI(2 * P_N + A_N);
    int* icur = carveI(2 * P_N + A_N);
    int* icsr = carveI(3 * E_N);
    int* isum = carveI(3 * 256);

    int* deg0 = ideg; int* deg1 = deg0 + P_N; int* deg2 = deg1 + P_N;
    int* cur0 = icur; int* cur1 = cur0 + P_N; int* cur2 = cur1 + P_N;
    int* csr0 = icsr; int* csr1 = csr0 + E_N; int* csr2 = csr1 + E_N;
    int* sum0 = isum; int* sum1 = sum0 + 256; int* sum2 = sum1 + 256;

    float* oaOut = (float*)d_out;                  // A_N * C_CLS
    float* opOut = oaOut + (size_t)A_N * C_CLS;    // P_N * H_DIM

    auto gemm = [&](const u16* a0, const u16* b0, const u16* a1, const u16* b1,
                    const u16* a2, const u16* b2, int nseg, const float* bias,
                    float* c32, u16* c16, int N, int K, int M, int relu) {
        dim3 grid((M + GBM - 1) / GBM, (N + GBN - 1) / GBN);
        gemm_mfma2<<<grid, 256, 0, stream>>>(a0, a1, a2, b0, b1, b2, nseg, bias, c32, c16, N, K, M, relu);
    };

    // ---- weight / input conversions ----
    xconv_kernel<<<((A_N * DIN / 4) + 255) / 256, 256, 0, stream>>>(x_author, XA16, A_N * DIN / 4);
    xconv_kernel<<<((P_N * DIN / 4) + 255) / 256, 256, 0, stream>>>(x_paper,  XP16, P_N * DIN / 4);
    wconv_kernel<<<(DIN * H_DIM + 255) / 256, 256, 0, stream>>>(embWa, embWaT, DIN, H_DIM, 1);
    wconv_kernel<<<(DIN * H_DIM + 255) / 256, 256, 0, stream>>>(embWp, embWpT, DIN, H_DIM, 1);
    wconv_kernel<<<(6 * H_DIM * H_DIM + 255) / 256, 256, 0, stream>>>(Wself,  WsT, H_DIM, H_DIM, 6);
    wconv_kernel<<<(6 * H_DIM * H_DIM + 255) / 256, 256, 0, stream>>>(Wneigh, WnT, H_DIM, H_DIM, 6);
    wsum_kernel<<<(2 * H_DIM * H_DIM + 255) / 256, 256, 0, stream>>>(Wself, WsumT);
    bsum_kernel<<<2, 256, 0, stream>>>(bconv, BSUM);
    wconv_kernel<<<(H_DIM * H_DIM + 255) / 256, 256, 0, stream>>>(pW1a, pW1aT, H_DIM, H_DIM, 1);
    wconv_kernel<<<(H_DIM * C_CLS + 255) / 256, 256, 0, stream>>>(pW2a, pW2aT, H_DIM, C_CLS, 1);
    wconv_kernel<<<(H_DIM * H_DIM + 255) / 256, 256, 0, stream>>>(pW1p, pW1pT, H_DIM, H_DIM, 1);
    wconv_kernel<<<(H_DIM * H_DIM + 255) / 256, 256, 0, stream>>>(pW2p, pW2pT, H_DIM, H_DIM, 1);

    // ---- CSR build ----
    hipMemsetAsync(ideg, 0, (size_t)(2 * P_N + A_N) * sizeof(int), stream);
    const int eB = (E_N + 255) / 256;
    degi_kernel<<<eB, 256, 0, stream>>>(e0d, deg0, E_N);
    degi_kernel<<<eB, 256, 0, stream>>>(e1d, deg1, E_N);
    degi_kernel<<<eB, 256, 0, stream>>>(e2d, deg2, E_N);

    auto build_scan = [&](int* deg, int* cur, int* sums, int n) {
        int nc = (n + 1023) / 1024;
        scan1_kernel<<<nc, 256, 0, stream>>>(deg, cur, sums, n);
        scan2_kernel<<<1, 256, 0, stream>>>(sums, nc);
        scan3_kernel<<<(n + 255) / 256, 256, 0, stream>>>(cur, sums, n);
    };
    build_scan(deg0, cur0, sum0, P_N);
    build_scan(deg1, cur1, sum1, P_N);
    build_scan(deg2, cur2, sum2, A_N);

    csr_fill_kernel<<<eB, 256, 0, stream>>>(e0s, e0d, cur0, csr0, E_N);
    csr_fill_kernel<<<eB, 256, 0, stream>>>(e1s, e1d, cur1, csr1, E_N);
    csr_fill_kernel<<<eB, 256, 0, stream>>>(e2s, e2d, cur2, csr2, E_N);

    // ---- input embeddings (bf16 out) ----
    gemm(XA16, embWaT, 0, 0, 0, 0, 1, embba, nullptr, HA16, A_N, DIN, H_DIM, 0);
    gemm(XP16, embWpT, 0, 0, 0, 0, 1, embbp, nullptr, HP16, P_N, DIN, H_DIM, 0);

    const int gaBlkP = (P_N * 32 + 255) / 256;
    const int gaBlkA = (A_N * 32 + 255) / 256;
    const size_t W2 = (size_t)H_DIM * H_DIM;

    for (int l = 0; l < 2; ++l) {
        // aggregations (read pre-update H)
        gather_mean_kernel<<<gaBlkP, 256, 0, stream>>>(HA16, cur0, deg0, csr0, AGG0, P_N);
        gather_mean_kernel<<<gaBlkP, 256, 0, stream>>>(HP16, cur1, deg1, csr1, AGG1, P_N);
        gather_mean_kernel<<<gaBlkA, 256, 0, stream>>>(HP16, cur2, deg2, csr2, AGGA, A_N);

        // paper: hp@(Ws0+Ws1) + agg0@Wn0 + agg1@Wn1 + (b0+b1), then relu+residual+LN in-place
        gemm_ln<<<(P_N + 127) / 128, 256, 0, stream>>>(
            HP16, AGG0, AGG1,
            WsumT + (size_t)l * W2, WnT + (size_t)(l * 3 + 0) * W2, WnT + (size_t)(l * 3 + 1) * W2,
            3, BSUM + l * H_DIM, lngp, lnbp, HP16, P_N);

        // author: ha@Ws2 + aggA@Wn2 + b2, then relu+residual+LN in-place
        gemm_ln<<<(A_N + 127) / 128, 256, 0, stream>>>(
            HA16, AGGA, (const u16*)nullptr,
            WsT + (size_t)(l * 3 + 2) * W2, WnT + (size_t)(l * 3 + 2) * W2, (const u16*)nullptr,
            2, bconv + (size_t)(l * 3 + 2) * H_DIM, lnga, lnba, HA16, A_N);
    }

    // ---- output heads ----
    u16* TMPA16 = AGGA;   // free after layers
    u16* TMPP16 = AGG0;
    gemm(HA16, pW1aT, 0, 0, 0, 0, 1, pb1a, nullptr, TMPA16, A_N, H_DIM, H_DIM, 1);
    gemm(TMPA16, pW2aT, 0, 0, 0, 0, 1, pb2a, oaOut, nullptr, A_N, H_DIM, C_CLS, 0);
    logsoftmax_kernel<<<(A_N * 64 + 255) / 256, 256, 0, stream>>>(oaOut, A_N, C_CLS);

    gemm(HP16, pW1pT, 0, 0, 0, 0, 1, pb1p, nullptr, TMPP16, P_N, H_DIM, H_DIM, 1);
    gemm(TMPP16, pW2pT, 0, 0, 0, 0, 1, nullptr, opOut, nullptr, P_N, H_DIM, H_DIM, 0);
}

// Round 4
// 1157.020 us; speedup vs baseline: 1.0326x; 1.0326x over previous
//
#include <hip/hip_runtime.h>

#define A_N   50000
#define P_N   100000
#define DIN   128
#define H_DIM 256
#define C_CLS 40
#define E_N   300000
#define EPS_LN 1e-5f

typedef short bf16x8 __attribute__((ext_vector_type(8)));
typedef float f32x4  __attribute__((ext_vector_type(4)));
typedef unsigned short u16;

__device__ __forceinline__ u16 f2bf(float x) {
    union { float f; unsigned u; } v; v.f = x;
    unsigned r = v.u + 0x7fff + ((v.u >> 16) & 1);
    return (u16)(r >> 16);
}
__device__ __forceinline__ float bf2f(u16 h) {
    union { unsigned u; float f; } v; v.u = ((unsigned)h) << 16;
    return v.f;
}

// async global->LDS, 16 B per lane; lds base must be wave-uniform (HW scatters lane*16)
__device__ __forceinline__ void gl2lds16(const u16* g, u16* ldsbase) {
    __builtin_amdgcn_global_load_lds(
        (const __attribute__((address_space(1))) unsigned int*)g,
        (__attribute__((address_space(3))) unsigned int*)ldsbase, 16, 0, 0);
}

// ================= general bf16 MFMA GEMM: C[N,M] = sum_seg A_seg[N,K] @ (BT_seg[M,K])^T ======
// 128x128 tile, BK=32, 256 threads (4 waves), wave = 64x64 via 4x4 of 16x16x32 MFMA.
// LDS [row][32] unpadded (global_load_lds layout); frag b128 reads are bank-balanced.
#define GBN 128
#define GBM 128

__launch_bounds__(256)
__global__ void gemm_mfma2(const u16* __restrict__ A0, const u16* __restrict__ A1,
                           const u16* __restrict__ A2,
                           const u16* __restrict__ B0, const u16* __restrict__ B1,
                           const u16* __restrict__ B2,
                           int nseg, const float* __restrict__ bias,
                           float* __restrict__ C32, u16* __restrict__ C16,
                           int N, int K, int M, int relu)
{
    __shared__ u16 As[GBN * 32];   // 8 KB
    __shared__ u16 Bs[GBM * 32];   // 8 KB

    const int tid  = threadIdx.x;
    const int wave = tid >> 6;
    const int lane = tid & 63;
    const int n0 = blockIdx.y * GBN;
    const int m0 = blockIdx.x * GBM;
    const int wrow = (wave >> 1) * 64;
    const int wcol = (wave & 1) * 64;
    const int lm   = lane & 15;
    const int quad = lane >> 4;
    const int rg = lane >> 2;      // staging: 4 lanes/row (64 B rows), 16 rows/instr
    const int ch = lane & 3;       // 16B chunk within row

    f32x4 acc[4][4];
    #pragma unroll
    for (int i = 0; i < 4; ++i)
        #pragma unroll
        for (int j = 0; j < 4; ++j)
            acc[i][j] = (f32x4)0.0f;

    for (int seg = 0; seg < nseg; ++seg) {
        const u16* Aseg = (seg == 0) ? A0 : (seg == 1) ? A1 : A2;
        const u16* Bseg = (seg == 0) ? B0 : (seg == 1) ? B1 : B2;

        for (int k0 = 0; k0 < K; k0 += 32) {
            __syncthreads();   // previous tile fully consumed before overwrite
            #pragma unroll
            for (int i = 0; i < 2; ++i) {
                int lr = wave * 32 + i * 16;
                int grow = n0 + lr + rg; if (grow > N - 1) grow = N - 1;
                gl2lds16(Aseg + (size_t)grow * K + k0 + ch * 8, &As[lr * 32]);
            }
            #pragma unroll
            for (int i = 0; i < 2; ++i) {
                int lr = wave * 32 + i * 16;
                int brow = m0 + lr + rg; if (brow > M - 1) brow = M - 1;
                gl2lds16(Bseg + (size_t)brow * K + k0 + ch * 8, &Bs[lr * 32]);
            }
            __syncthreads();   // vmcnt drain + barrier

            bf16x8 af[4], bfr[4];
            #pragma unroll
            for (int i = 0; i < 4; ++i)
                af[i] = *(const bf16x8*)&As[(wrow + i * 16 + lm) * 32 + quad * 8];
            #pragma unroll
            for (int j = 0; j < 4; ++j)
                bfr[j] = *(const bf16x8*)&Bs[(wcol + j * 16 + lm) * 32 + quad * 8];
            #pragma unroll
            for (int i = 0; i < 4; ++i)
                #pragma unroll
                for (int j = 0; j < 4; ++j)
                    acc[i][j] = __builtin_amdgcn_mfma_f32_16x16x32_bf16(af[i], bfr[j], acc[i][j], 0, 0, 0);
        }
    }

    // epilogue: C/D layout col=lane&15, row=quad*4+reg
    float bj[4];
    #pragma unroll
    for (int j = 0; j < 4; ++j) {
        int gcol = m0 + wcol + j * 16 + lm;
        bj[j] = (bias && gcol < M) ? bias[gcol] : 0.f;
    }
    #pragma unroll
    for (int i = 0; i < 4; ++i) {
        #pragma unroll
        for (int r = 0; r < 4; ++r) {
            int grow = n0 + wrow + i * 16 + quad * 4 + r;
            if (grow >= N) continue;
            #pragma unroll
            for (int j = 0; j < 4; ++j) {
                int gcol = m0 + wcol + j * 16 + lm;
                if (gcol >= M) continue;
                float v = acc[i][j][r] + bj[j];
                if (relu) v = fmaxf(v, 0.f);
                if (C32) C32[(size_t)grow * M + gcol] = v;
                if (C16) C16[(size_t)grow * M + gcol] = f2bf(v);
            }
        }
    }
}

// ========== fused layer GEMM + relu + residual + LayerNorm, in-place on H (bf16) ==========
// v4: v1 skeleton (64 rows/block, BK=32, 2 barriers/step, ~5 blk/CU occupancy) with the
// wave->output mapping rebalanced from (16 rows x 256 cols, 17 LDS reads / 16 MFMA) to
// (64x64 tile, 8 reads / 16 MFMA) -- the gemm_mfma2 geometry.  acc stays 64 VGPR.
// LN becomes a cross-wave reduction: each wave owns a 64-col quarter of the same 64 rows;
// per-row partial (sum,sumsq) -> 2 KB LDS -> barrier -> finalize own quarter.
// Safe in-place: block reads only its own 64 A rows; each H element is read (residual)
// and written by the same lane, read-before-write; pass-1 reads all precede the barrier.
__launch_bounds__(256)
__global__ void gemm_ln(const u16* __restrict__ A0, const u16* __restrict__ A1,
                        const u16* __restrict__ A2,
                        const u16* __restrict__ B0, const u16* __restrict__ B1,
                        const u16* __restrict__ B2,
                        int nseg, const float* __restrict__ bias,
                        const float* __restrict__ lng, const float* __restrict__ lnb,
                        u16* __restrict__ H, int N)
{
    __shared__ u16 As[64 * 32];        // 4 KB
    __shared__ u16 Bs[256 * 32];       // 16 KB
    __shared__ float lnred[4][64][2];  // 2 KB per-wave per-row (sum, sumsq)

    const int tid  = threadIdx.x;
    const int wave = tid >> 6;
    const int lane = tid & 63;
    const int n0 = blockIdx.x * 64;
    const int lm   = lane & 15;
    const int quad = lane >> 4;
    const int rg = lane >> 2;          // staging: 4 lanes/row (64 B rows), 16 rows/instr
    const int ch = lane & 3;           // 16B chunk within row
    const int wcol = wave * 64;        // this wave's 64-col band

    f32x4 acc[4][4];
    #pragma unroll
    for (int i = 0; i < 4; ++i)
        #pragma unroll
        for (int j = 0; j < 4; ++j) acc[i][j] = (f32x4)0.0f;

    for (int seg = 0; seg < nseg; ++seg) {
        const u16* Aseg = (seg == 0) ? A0 : (seg == 1) ? A1 : A2;
        const u16* Bseg = (seg == 0) ? B0 : (seg == 1) ? B1 : B2;

        for (int k0 = 0; k0 < H_DIM; k0 += 32) {
            __syncthreads();
            {   // A: 64 rows, wave stages its own 16
                int lr = wave * 16;
                int grow = n0 + lr + rg; if (grow > N - 1) grow = N - 1;
                gl2lds16(Aseg + (size_t)grow * H_DIM + k0 + ch * 8, &As[lr * 32]);
            }
            #pragma unroll
            for (int i = 0; i < 4; ++i) {   // B: 256 rows, wave stages 64
                int lr = wave * 64 + i * 16;
                gl2lds16(Bseg + (size_t)(lr + rg) * H_DIM + k0 + ch * 8, &Bs[lr * 32]);
            }
            __syncthreads();

            bf16x8 af[4], bfr[4];
            #pragma unroll
            for (int i = 0; i < 4; ++i)
                af[i] = *(const bf16x8*)&As[(i * 16 + lm) * 32 + quad * 8];
            #pragma unroll
            for (int j = 0; j < 4; ++j)
                bfr[j] = *(const bf16x8*)&Bs[(wcol + j * 16 + lm) * 32 + quad * 8];
            #pragma unroll
            for (int i = 0; i < 4; ++i)
                #pragma unroll
                for (int j = 0; j < 4; ++j)
                    acc[i][j] = __builtin_amdgcn_mfma_f32_16x16x32_bf16(af[i], bfr[j], acc[i][j], 0, 0, 0);
        }
    }

    // ---- epilogue ----
    // lane's elements: row(i,r) = n0 + i*16 + quad*4 + r (uniform over lm);
    //                  col(j)   = wcol + j*16 + lm
    float bj[4];
    #pragma unroll
    for (int j = 0; j < 4; ++j) bj[j] = bias[wcol + j * 16 + lm];

    // pass 1: per-row partial (sum, sumsq) over this wave's 64 cols
    #pragma unroll
    for (int i = 0; i < 4; ++i) {
        #pragma unroll
        for (int r = 0; r < 4; ++r) {
            int lrow = i * 16 + quad * 4 + r;
            int grow = n0 + lrow;
            int hrow = (grow < N) ? grow : (N - 1);   // clamp: garbage rows never written
            float s = 0.f, q = 0.f;
            #pragma unroll
            for (int j = 0; j < 4; ++j) {
                int col = wcol + j * 16 + lm;
                float x = fmaxf(acc[i][j][r] + bj[j], 0.f)
                        + bf2f(H[(size_t)hrow * H_DIM + col]);
                s += x; q += x * x;
            }
            #pragma unroll
            for (int off = 1; off < 16; off <<= 1) {
                s += __shfl_xor(s, off, 64);
                q += __shfl_xor(q, off, 64);
            }
            if (lm == 0) { lnred[wave][lrow][0] = s; lnred[wave][lrow][1] = q; }
        }
    }
    __syncthreads();

    // pass 2: finalize LN for own quarter, write bf16
    #pragma unroll
    for (int i = 0; i < 4; ++i) {
        #pragma unroll
        for (int r = 0; r < 4; ++r) {
            int lrow = i * 16 + quad * 4 + r;
            int grow = n0 + lrow;
            if (grow >= N) continue;
            float s = lnred[0][lrow][0] + lnred[1][lrow][0] + lnred[2][lrow][0] + lnred[3][lrow][0];
            float q = lnred[0][lrow][1] + lnred[1][lrow][1] + lnred[2][lrow][1] + lnred[3][lrow][1];
            float mean = s * (1.0f / H_DIM);
            float var  = q * (1.0f / H_DIM) - mean * mean;
            float inv  = rsqrtf(var + EPS_LN);
            #pragma unroll
            for (int j = 0; j < 4; ++j) {
                int col = wcol + j * 16 + lm;
                float x = fmaxf(acc[i][j][r] + bj[j], 0.f)
                        + bf2f(H[(size_t)grow * H_DIM + col]);
                H[(size_t)grow * H_DIM + col] = f2bf((x - mean) * inv * lng[col] + lnb[col]);
            }
        }
    }
}

// ---------------- conversions ----------------
__global__ void xconv_kernel(const float* __restrict__ x, u16* __restrict__ o, int n4)
{
    int i = blockIdx.x * blockDim.x + threadIdx.x;
    if (i >= n4) return;
    float4 v = ((const float4*)x)[i];
    ushort4 u;
    u.x = f2bf(v.x); u.y = f2bf(v.y); u.z = f2bf(v.z); u.w = f2bf(v.w);
    ((ushort4*)o)[i] = u;
}

__global__ void wconv_kernel(const float* __restrict__ W, u16* __restrict__ WT,
                             int K, int M, int count)
{
    int idx = blockIdx.x * blockDim.x + threadIdx.x;
    int per = K * M;
    if (idx >= per * count) return;
    int b = idx / per, rem = idx - b * per;
    int k = rem / M, m = rem - k * M;
    WT[(size_t)b * per + (size_t)m * K + k] = f2bf(W[idx]);
}

__global__ void wsum_kernel(const float* __restrict__ Wself, u16* __restrict__ WT)
{
    int idx = blockIdx.x * blockDim.x + threadIdx.x;
    const int per = H_DIM * H_DIM;
    if (idx >= 2 * per) return;
    int l = idx / per, rem = idx - l * per;
    int k = rem / H_DIM, m = rem - k * H_DIM;
    float v = Wself[(size_t)(l * 3 + 0) * per + rem] + Wself[(size_t)(l * 3 + 1) * per + rem];
    WT[(size_t)l * per + (size_t)m * H_DIM + k] = f2bf(v);
}

__global__ void bsum_kernel(const float* __restrict__ bconv, float* __restrict__ bsum)
{
    int idx = blockIdx.x * blockDim.x + threadIdx.x;
    if (idx >= 2 * H_DIM) return;
    int l = idx >> 8, j = idx & 255;
    bsum[idx] = bconv[(l * 3 + 0) * H_DIM + j] + bconv[(l * 3 + 1) * H_DIM + j];
}

// ---------------- CSR build ----------------
__global__ void degi_kernel(const int* __restrict__ dst, int* __restrict__ deg, int E)
{
    int i = blockIdx.x * blockDim.x + threadIdx.x;
    if (i < E) atomicAdd(&deg[dst[i]], 1);
}

__device__ __forceinline__ int block_exscan256(int val, int* lds, int* total)
{
    int t = threadIdx.x;
    lds[t] = val;
    __syncthreads();
    #pragma unroll
    for (int off = 1; off < 256; off <<= 1) {
        int y = (t >= off) ? lds[t - off] : 0;
        __syncthreads();
        lds[t] += y;
        __syncthreads();
    }
    int inc = lds[t];
    *total = lds[255];
    __syncthreads();
    return inc - val;
}

__global__ void scan1_kernel(const int* __restrict__ in, int* __restrict__ out,
                             int* __restrict__ sums, int n)
{
    __shared__ int lds[256];
    int t = threadIdx.x;
    int base = blockIdx.x * 1024 + t * 4;
    int v0 = 0, v1 = 0, v2 = 0, v3 = 0;
    if (base + 3 < n) {
        int4 q = *(const int4*)(in + base);
        v0 = q.x; v1 = q.y; v2 = q.z; v3 = q.w;
    } else {
        if (base     < n) v0 = in[base];
        if (base + 1 < n) v1 = in[base + 1];
        if (base + 2 < n) v2 = in[base + 2];
    }
    int tot = v0 + v1 + v2 + v3, bt;
    int ex = block_exscan256(tot, lds, &bt);
    if (base     < n) out[base]     = ex;
    if (base + 1 < n) out[base + 1] = ex + v0;
    if (base + 2 < n) out[base + 2] = ex + v0 + v1;
    if (base + 3 < n) out[base + 3] = ex + v0 + v1 + v2;
    if (t == 0) sums[blockIdx.x] = bt;
}

__global__ void scan2_kernel(int* __restrict__ sums, int nc)
{
    __shared__ int lds[256];
    int t = threadIdx.x;
    int v = (t < nc) ? sums[t] : 0;
    int bt;
    int ex = block_exscan256(v, lds, &bt);
    if (t < nc) sums[t] = ex;
}

__global__ void scan3_kernel(int* __restrict__ cur, const int* __restrict__ sums, int n)
{
    int i = blockIdx.x * blockDim.x + threadIdx.x;
    if (i < n) cur[i] += sums[i >> 10];
}

__global__ void csr_fill_kernel(const int* __restrict__ src, const int* __restrict__ dst,
                                int* __restrict__ cur, int* __restrict__ csr, int E)
{
    int e = blockIdx.x * blockDim.x + threadIdx.x;
    if (e < E) {
        int pos = atomicAdd(&cur[dst[e]], 1);
        csr[pos] = src[e];
    }
}

// ---------------- pull-style mean aggregation: 2 dst rows per wave, 16 B/lane ----------------
typedef unsigned short u16x8 __attribute__((ext_vector_type(8)));

__launch_bounds__(256)
__global__ void gather_mean_kernel(const u16* __restrict__ h, const int* __restrict__ cur,
                                   const int* __restrict__ deg, const int* __restrict__ csr,
                                   u16* __restrict__ agg, int N)
{
    int gid = blockIdx.x * blockDim.x + threadIdx.x;
    int d = gid >> 5;
    if (d >= N) return;
    int l = gid & 31;               // 32 chunks of 8 bf16 per 256-wide row
    int dg = deg[d];
    int o  = cur[d] - dg;
    float a[8] = {};
    for (int i = 0; i < dg; ++i) {
        int s = csr[o + i];
        u16x8 v = *(const u16x8*)(h + (size_t)s * H_DIM + l * 8);
        #pragma unroll
        for (int t = 0; t < 8; ++t) a[t] += bf2f(v[t]);
    }
    float r = (dg > 0) ? (1.0f / (float)dg) : 0.f;
    u16x8 u;
    #pragma unroll
    for (int t = 0; t < 8; ++t) u[t] = f2bf(a[t] * r);
    *(u16x8*)(agg + (size_t)d * H_DIM + l * 8) = u;
}

// ---------------- in-place log_softmax ----------------
__launch_bounds__(256)
__global__ void logsoftmax_kernel(float* __restrict__ x, int N, int C)
{
    int gid = blockIdx.x * blockDim.x + threadIdx.x;
    int row = gid >> 6;
    if (row >= N) return;
    int lane = threadIdx.x & 63;
    float v = (lane < C) ? x[(size_t)row * C + lane] : -3.0e38f;
    float m = v;
    #pragma unroll
    for (int off = 32; off; off >>= 1) m = fmaxf(m, __shfl_xor(m, off, 64));
    float e = (lane < C) ? __expf(v - m) : 0.f;
    float s = e;
    #pragma unroll
    for (int off = 32; off; off >>= 1) s += __shfl_xor(s, off, 64);
    float ls = logf(s);
    if (lane < C) x[(size_t)row * C + lane] = v - m - ls;
}

// ======================================================================================
extern "C" void kernel_launch(void* const* d_in, const int* in_sizes, int n_in,
                              void* d_out, int out_size, void* d_ws, size_t ws_size,
                              hipStream_t stream)
{
    const float* x_author = (const float*)d_in[0];
    const float* x_paper  = (const float*)d_in[1];
    const int* e0s = (const int*)d_in[2]; const int* e0d = (const int*)d_in[3];
    const int* e1s = (const int*)d_in[4]; const int* e1d = (const int*)d_in[5];
    const int* e2s = (const int*)d_in[6]; const int* e2d = (const int*)d_in[7];
    const float* embWa = (const float*)d_in[8];  const float* embba = (const float*)d_in[9];
    const float* embWp = (const float*)d_in[10]; const float* embbp = (const float*)d_in[11];
    const float* Wself  = (const float*)d_in[12];
    const float* Wneigh = (const float*)d_in[13];
    const float* bconv  = (const float*)d_in[14];
    const float* lnga = (const float*)d_in[15]; const float* lnba = (const float*)d_in[16];
    const float* lngp = (const float*)d_in[17]; const float* lnbp = (const float*)d_in[18];
    const float* pW1a = (const float*)d_in[19]; const float* pb1a = (const float*)d_in[20];
    const float* pW2a = (const float*)d_in[21]; const float* pb2a = (const float*)d_in[22];
    const float* pW1p = (const float*)d_in[23]; const float* pb1p = (const float*)d_in[24];
    const float* pW2p = (const float*)d_in[25];

    // ---- workspace carve ----
    char* wp = (char*)d_ws;
    auto carveF = [&](size_t n) { float* p = (float*)wp; wp += n * sizeof(float); return p; };
    auto carveU = [&](size_t n) { u16* p = (u16*)wp; wp += n * sizeof(u16); return p; };
    auto carveI = [&](size_t n) { int* p = (int*)wp; wp += n * sizeof(int); return p; };

    float* BSUM = carveF(2 * H_DIM);

    u16* HA16  = carveU((size_t)A_N * H_DIM);
    u16* HP16  = carveU((size_t)P_N * H_DIM);
    u16* AGG0  = carveU((size_t)P_N * H_DIM);
    u16* AGG1  = carveU((size_t)P_N * H_DIM);
    u16* AGGA  = carveU((size_t)A_N * H_DIM);
    u16* XA16  = carveU((size_t)A_N * DIN);
    u16* XP16  = carveU((size_t)P_N * DIN);
    u16* WsT    = carveU(6 * H_DIM * H_DIM);
    u16* WnT    = carveU(6 * H_DIM * H_DIM);
    u16* WsumT  = carveU(2 * H_DIM * H_DIM);
    u16* embWaT = carveU(DIN * H_DIM);
    u16* embWpT = carveU(DIN * H_DIM);
    u16* pW1aT  = carveU(H_DIM * H_DIM);
    u16* pW2aT  = carveU(H_DIM * C_CLS);
    u16* pW1pT  = carveU(H_DIM * H_DIM);
    u16* pW2pT  = carveU(H_DIM * H_DIM);

    int* ideg = carveI(2 * P_N + A_N);
    int* icur = carveI(2 * P_N + A_N);
    int* icsr = carveI(3 * E_N);
    int* isum = carveI(3 * 256);

    int* deg0 = ideg; int* deg1 = deg0 + P_N; int* deg2 = deg1 + P_N;
    int* cur0 = icur; int* cur1 = cur0 + P_N; int* cur2 = cur1 + P_N;
    int* csr0 = icsr; int* csr1 = csr0 + E_N; int* csr2 = csr1 + E_N;
    int* sum0 = isum; int* sum1 = sum0 + 256; int* sum2 = sum1 + 256;

    float* oaOut = (float*)d_out;                  // A_N * C_CLS
    float* opOut = oaOut + (size_t)A_N * C_CLS;    // P_N * H_DIM

    auto gemm = [&](const u16* a0, const u16* b0, const u16* a1, const u16* b1,
                    const u16* a2, const u16* b2, int nseg, const float* bias,
                    float* c32, u16* c16, int N, int K, int M, int relu) {
        dim3 grid((M + GBM - 1) / GBM, (N + GBN - 1) / GBN);
        gemm_mfma2<<<grid, 256, 0, stream>>>(a0, a1, a2, b0, b1, b2, nseg, bias, c32, c16, N, K, M, relu);
    };

    // ---- weight / input conversions ----
    xconv_kernel<<<((A_N * DIN / 4) + 255) / 256, 256, 0, stream>>>(x_author, XA16, A_N * DIN / 4);
    xconv_kernel<<<((P_N * DIN / 4) + 255) / 256, 256, 0, stream>>>(x_paper,  XP16, P_N * DIN / 4);
    wconv_kernel<<<(DIN * H_DIM + 255) / 256, 256, 0, stream>>>(embWa, embWaT, DIN, H_DIM, 1);
    wconv_kernel<<<(DIN * H_DIM + 255) / 256, 256, 0, stream>>>(embWp, embWpT, DIN, H_DIM, 1);
    wconv_kernel<<<(6 * H_DIM * H_DIM + 255) / 256, 256, 0, stream>>>(Wself,  WsT, H_DIM, H_DIM, 6);
    wconv_kernel<<<(6 * H_DIM * H_DIM + 255) / 256, 256, 0, stream>>>(Wneigh, WnT, H_DIM, H_DIM, 6);
    wsum_kernel<<<(2 * H_DIM * H_DIM + 255) / 256, 256, 0, stream>>>(Wself, WsumT);
    bsum_kernel<<<2, 256, 0, stream>>>(bconv, BSUM);
    wconv_kernel<<<(H_DIM * H_DIM + 255) / 256, 256, 0, stream>>>(pW1a, pW1aT, H_DIM, H_DIM, 1);
    wconv_kernel<<<(H_DIM * C_CLS + 255) / 256, 256, 0, stream>>>(pW2a, pW2aT, H_DIM, C_CLS, 1);
    wconv_kernel<<<(H_DIM * H_DIM + 255) / 256, 256, 0, stream>>>(pW1p, pW1pT, H_DIM, H_DIM, 1);
    wconv_kernel<<<(H_DIM * H_DIM + 255) / 256, 256, 0, stream>>>(pW2p, pW2pT, H_DIM, H_DIM, 1);

    // ---- CSR build ----
    hipMemsetAsync(ideg, 0, (size_t)(2 * P_N + A_N) * sizeof(int), stream);
    const int eB = (E_N + 255) / 256;
    degi_kernel<<<eB, 256, 0, stream>>>(e0d, deg0, E_N);
    degi_kernel<<<eB, 256, 0, stream>>>(e1d, deg1, E_N);
    degi_kernel<<<eB, 256, 0, stream>>>(e2d, deg2, E_N);

    auto build_scan = [&](int* deg, int* cur, int* sums, int n) {
        int nc = (n + 1023) / 1024;
        scan1_kernel<<<nc, 256, 0, stream>>>(deg, cur, sums, n);
        scan2_kernel<<<1, 256, 0, stream>>>(sums, nc);
        scan3_kernel<<<(n + 255) / 256, 256, 0, stream>>>(cur, sums, n);
    };
    build_scan(deg0, cur0, sum0, P_N);
    build_scan(deg1, cur1, sum1, P_N);
    build_scan(deg2, cur2, sum2, A_N);

    csr_fill_kernel<<<eB, 256, 0, stream>>>(e0s, e0d, cur0, csr0, E_N);
    csr_fill_kernel<<<eB, 256, 0, stream>>>(e1s, e1d, cur1, csr1, E_N);
    csr_fill_kernel<<<eB, 256, 0, stream>>>(e2s, e2d, cur2, csr2, E_N);

    // ---- input embeddings (bf16 out) ----
    gemm(XA16, embWaT, 0, 0, 0, 0, 1, embba, nullptr, HA16, A_N, DIN, H_DIM, 0);
    gemm(XP16, embWpT, 0, 0, 0, 0, 1, embbp, nullptr, HP16, P_N, DIN, H_DIM, 0);

    const int gaBlkP = (P_N * 32 + 255) / 256;
    const int gaBlkA = (A_N * 32 + 255) / 256;
    const size_t W2 = (size_t)H_DIM * H_DIM;

    for (int l = 0; l < 2; ++l) {
        // aggregations (read pre-update H)
        gather_mean_kernel<<<gaBlkP, 256, 0, stream>>>(HA16, cur0, deg0, csr0, AGG0, P_N);
        gather_mean_kernel<<<gaBlkP, 256, 0, stream>>>(HP16, cur1, deg1, csr1, AGG1, P_N);
        gather_mean_kernel<<<gaBlkA, 256, 0, stream>>>(HP16, cur2, deg2, csr2, AGGA, A_N);

        // paper: hp@(Ws0+Ws1) + agg0@Wn0 + agg1@Wn1 + (b0+b1), then relu+residual+LN in-place
        gemm_ln<<<(P_N + 63) / 64, 256, 0, stream>>>(
            HP16, AGG0, AGG1,
            WsumT + (size_t)l * W2, WnT + (size_t)(l * 3 + 0) * W2, WnT + (size_t)(l * 3 + 1) * W2,
            3, BSUM + l * H_DIM, lngp, lnbp, HP16, P_N);

        // author: ha@Ws2 + aggA@Wn2 + b2, then relu+residual+LN in-place
        gemm_ln<<<(A_N + 63) / 64, 256, 0, stream>>>(
            HA16, AGGA, (const u16*)nullptr,
            WsT + (size_t)(l * 3 + 2) * W2, WnT + (size_t)(l * 3 + 2) * W2, (const u16*)nullptr,
            2, bconv + (size_t)(l * 3 + 2) * H_DIM, lnga, lnba, HA16, A_N);
    }

    // ---- output heads ----
    u16* TMPA16 = AGGA;   // free after layers
    u16* TMPP16 = AGG0;
    gemm(HA16, pW1aT, 0, 0, 0, 0, 1, pb1a, nullptr, TMPA16, A_N, H_DIM, H_DIM, 1);
    gemm(TMPA16, pW2aT, 0, 0, 0, 0, 1, pb2a, oaOut, nullptr, A_N, H_DIM, C_CLS, 0);
    logsoftmax_kernel<<<(A_N * 64 + 255) / 256, 256, 0, stream>>>(oaOut, A_N, C_CLS);

    gemm(HP16, pW1pT, 0, 0, 0, 0, 1, pb1p, nullptr, TMPP16, P_N, H_DIM, H_DIM, 1);
    gemm(TMPP16, pW2pT, 0, 0, 0, 0, 1, nullptr, opOut, nullptr, P_N, H_DIM, H_DIM, 0);
}

// Round 5
// 1068.111 us; speedup vs baseline: 1.1186x; 1.0832x over previous
//
#include <hip/hip_runtime.h>

#define A_N   50000
#define P_N   100000
#define DIN   128
#define H_DIM 256
#define C_CLS 40
#define E_N   300000
#define EPS_LN 1e-5f

typedef short bf16x8 __attribute__((ext_vector_type(8)));
typedef float f32x4  __attribute__((ext_vector_type(4)));
typedef unsigned short u16;

__device__ __forceinline__ u16 f2bf(float x) {
    union { float f; unsigned u; } v; v.f = x;
    unsigned r = v.u + 0x7fff + ((v.u >> 16) & 1);
    return (u16)(r >> 16);
}
__device__ __forceinline__ float bf2f(u16 h) {
    union { unsigned u; float f; } v; v.u = ((unsigned)h) << 16;
    return v.f;
}

// async global->LDS, 16 B per lane; lds base must be wave-uniform (HW scatters lane*16)
__device__ __forceinline__ void gl2lds16(const u16* g, u16* ldsbase) {
    __builtin_amdgcn_global_load_lds(
        (const __attribute__((address_space(1))) unsigned int*)g,
        (__attribute__((address_space(3))) unsigned int*)ldsbase, 16, 0, 0);
}

// ================= general bf16 MFMA GEMM: C[N,M] = sum_seg A_seg[N,K] @ (BT_seg[M,K])^T ======
// 128x128 tile, BK=32, 256 threads (4 waves), wave = 64x64 via 4x4 of 16x16x32 MFMA.
// LDS [row][32] unpadded (global_load_lds layout); frag b128 reads are bank-balanced.
#define GBN 128
#define GBM 128

__launch_bounds__(256)
__global__ void gemm_mfma2(const u16* __restrict__ A0, const u16* __restrict__ A1,
                           const u16* __restrict__ A2,
                           const u16* __restrict__ B0, const u16* __restrict__ B1,
                           const u16* __restrict__ B2,
                           int nseg, const float* __restrict__ bias,
                           float* __restrict__ C32, u16* __restrict__ C16,
                           int N, int K, int M, int relu)
{
    __shared__ u16 As[GBN * 32];   // 8 KB
    __shared__ u16 Bs[GBM * 32];   // 8 KB

    const int tid  = threadIdx.x;
    const int wave = tid >> 6;
    const int lane = tid & 63;
    const int n0 = blockIdx.y * GBN;
    const int m0 = blockIdx.x * GBM;
    const int wrow = (wave >> 1) * 64;
    const int wcol = (wave & 1) * 64;
    const int lm   = lane & 15;
    const int quad = lane >> 4;
    const int rg = lane >> 2;      // staging: 4 lanes/row (64 B rows), 16 rows/instr
    const int ch = lane & 3;       // 16B chunk within row

    f32x4 acc[4][4];
    #pragma unroll
    for (int i = 0; i < 4; ++i)
        #pragma unroll
        for (int j = 0; j < 4; ++j)
            acc[i][j] = (f32x4)0.0f;

    for (int seg = 0; seg < nseg; ++seg) {
        const u16* Aseg = (seg == 0) ? A0 : (seg == 1) ? A1 : A2;
        const u16* Bseg = (seg == 0) ? B0 : (seg == 1) ? B1 : B2;

        for (int k0 = 0; k0 < K; k0 += 32) {
            __syncthreads();   // previous tile fully consumed before overwrite
            #pragma unroll
            for (int i = 0; i < 2; ++i) {
                int lr = wave * 32 + i * 16;
                int grow = n0 + lr + rg; if (grow > N - 1) grow = N - 1;
                gl2lds16(Aseg + (size_t)grow * K + k0 + ch * 8, &As[lr * 32]);
            }
            #pragma unroll
            for (int i = 0; i < 2; ++i) {
                int lr = wave * 32 + i * 16;
                int brow = m0 + lr + rg; if (brow > M - 1) brow = M - 1;
                gl2lds16(Bseg + (size_t)brow * K + k0 + ch * 8, &Bs[lr * 32]);
            }
            __syncthreads();   // vmcnt drain + barrier

            bf16x8 af[4], bfr[4];
            #pragma unroll
            for (int i = 0; i < 4; ++i)
                af[i] = *(const bf16x8*)&As[(wrow + i * 16 + lm) * 32 + quad * 8];
            #pragma unroll
            for (int j = 0; j < 4; ++j)
                bfr[j] = *(const bf16x8*)&Bs[(wcol + j * 16 + lm) * 32 + quad * 8];
            #pragma unroll
            for (int i = 0; i < 4; ++i)
                #pragma unroll
                for (int j = 0; j < 4; ++j)
                    acc[i][j] = __builtin_amdgcn_mfma_f32_16x16x32_bf16(af[i], bfr[j], acc[i][j], 0, 0, 0);
        }
    }

    // epilogue: C/D layout col=lane&15, row=quad*4+reg
    float bj[4];
    #pragma unroll
    for (int j = 0; j < 4; ++j) {
        int gcol = m0 + wcol + j * 16 + lm;
        bj[j] = (bias && gcol < M) ? bias[gcol] : 0.f;
    }
    #pragma unroll
    for (int i = 0; i < 4; ++i) {
        #pragma unroll
        for (int r = 0; r < 4; ++r) {
            int grow = n0 + wrow + i * 16 + quad * 4 + r;
            if (grow >= N) continue;
            #pragma unroll
            for (int j = 0; j < 4; ++j) {
                int gcol = m0 + wcol + j * 16 + lm;
                if (gcol >= M) continue;
                float v = acc[i][j][r] + bj[j];
                if (relu) v = fmaxf(v, 0.f);
                if (C32) C32[(size_t)grow * M + gcol] = v;
                if (C16) C16[(size_t)grow * M + gcol] = f2bf(v);
            }
        }
    }
}

// ========== fused layer GEMM + relu + residual + LayerNorm, in-place on H (bf16) ==========
// v5: v1's EXACT geometry + epilogue (64 rows/block, 16r x 256c per wave, BK=32, acc[16])
// with the sync structure replaced by counted-vmcnt double-buffering (catalog T3+T4):
//   - As[2]/Bs[2] double buffers (40 KB -> 4 blocks/CU).
//   - per step: issue 5 gl2lds for tile t+1 into buf^1, s_waitcnt vmcnt(5) (waits tile t's
//     5 loads, leaves t+1's in flight -- NEVER drains to 0 mid-loop), s_barrier, compute
//     tile t, s_barrier (no waitcnt), flip.  Prefetch distance: 0 -> one compute phase.
//   - sched_barrier(0) after each barrier pins ds_read/MFMA inside their phase (rule #18).
//   - every wave stages exactly 5 loads/tile (A:1, B:4) -> vmcnt count is exact & uniform.
// v2-v4 falsified LDS-read-volume / bank-conflict theories (fewer reads & 0 conflicts both
// regressed); v1's limiter is the exposed stage latency this structure removes.
__launch_bounds__(256)
__global__ void gemm_ln(const u16* __restrict__ A0, const u16* __restrict__ A1,
                        const u16* __restrict__ A2,
                        const u16* __restrict__ B0, const u16* __restrict__ B1,
                        const u16* __restrict__ B2,
                        int nseg, const float* __restrict__ bias,
                        const float* __restrict__ lng, const float* __restrict__ lnb,
                        u16* __restrict__ H, int N)
{
    __shared__ u16 As[2][64 * 32];    // 2 x 4 KB
    __shared__ u16 Bs[2][256 * 32];   // 2 x 16 KB

    const int tid  = threadIdx.x;
    const int wave = tid >> 6;
    const int lane = tid & 63;
    const int n0 = blockIdx.x * 64;
    const int lm   = lane & 15;
    const int quad = lane >> 4;
    const int rg = lane >> 2;          // staging: 4 lanes/row (64 B rows), 16 rows/instr
    const int ch = lane & 3;           // 16B chunk within row

    f32x4 acc[16];
    #pragma unroll
    for (int j = 0; j < 16; ++j) acc[j] = (f32x4)0.0f;

    const int T = nseg * 8;            // K-steps of 32

    auto stage = [&](int t, int b) {
        const int seg = t >> 3;
        const int k0 = (t & 7) * 32;
        const u16* Aseg = (seg == 0) ? A0 : (seg == 1) ? A1 : A2;
        const u16* Bseg = (seg == 0) ? B0 : (seg == 1) ? B1 : B2;
        {   // A: 64 rows, wave stages its own 16
            int lr = wave * 16;
            int grow = n0 + lr + rg; if (grow > N - 1) grow = N - 1;
            gl2lds16(Aseg + (size_t)grow * H_DIM + k0 + ch * 8, &As[b][lr * 32]);
        }
        #pragma unroll
        for (int i = 0; i < 4; ++i) {   // B: 256 rows, wave stages 64
            int lr = wave * 64 + i * 16;
            gl2lds16(Bseg + (size_t)(lr + rg) * H_DIM + k0 + ch * 8, &Bs[b][lr * 32]);
        }
    };

    stage(0, 0);
    for (int t = 0; t < T; ++t) {
        if (t + 1 < T) {
            stage(t + 1, (t + 1) & 1);
            asm volatile("s_waitcnt vmcnt(5)" ::: "memory");  // tile t landed; t+1 in flight
        } else {
            asm volatile("s_waitcnt vmcnt(0)" ::: "memory");  // last tile: drain
        }
        __builtin_amdgcn_s_barrier();          // all waves' tile-t loads visible
        __builtin_amdgcn_sched_barrier(0);     // no ds_read hoists above this point

        const u16* ap = &As[t & 1][0];
        const u16* bp = &Bs[t & 1][0];
        bf16x8 af = *(const bf16x8*)&ap[(wave * 16 + lm) * 32 + quad * 8];
        #pragma unroll
        for (int j = 0; j < 16; ++j) {
            bf16x8 bfr = *(const bf16x8*)&bp[(j * 16 + lm) * 32 + quad * 8];
            acc[j] = __builtin_amdgcn_mfma_f32_16x16x32_bf16(af, bfr, acc[j], 0, 0, 0);
        }

        __builtin_amdgcn_sched_barrier(0);     // no ds_read sinks below (buf reused at t+2)
        __builtin_amdgcn_s_barrier();          // all waves done reading buf before restage
        __builtin_amdgcn_sched_barrier(0);
    }

    // epilogue (v1): per row relu + bias, + residual H, LN over 256 cols, write bf16
    #pragma unroll
    for (int r = 0; r < 4; ++r) {
        int grow = n0 + wave * 16 + quad * 4 + r;   // uniform across the 16 lm lanes
        if (grow >= N) continue;
        float v[16];
        float ps = 0.f, pq = 0.f;
        #pragma unroll
        for (int j = 0; j < 16; ++j) {
            int col = j * 16 + lm;
            float x = fmaxf(acc[j][r] + bias[col], 0.f);
            x += bf2f(H[(size_t)grow * H_DIM + col]);
            v[j] = x; ps += x; pq += x * x;
        }
        #pragma unroll
        for (int off = 1; off < 16; off <<= 1) {
            ps += __shfl_xor(ps, off, 64);
            pq += __shfl_xor(pq, off, 64);
        }
        float mean = ps * (1.0f / H_DIM);
        float var  = pq * (1.0f / H_DIM) - mean * mean;
        float inv  = rsqrtf(var + EPS_LN);
        #pragma unroll
        for (int j = 0; j < 16; ++j) {
            int col = j * 16 + lm;
            H[(size_t)grow * H_DIM + col] = f2bf((v[j] - mean) * inv * lng[col] + lnb[col]);
        }
    }
}

// ---------------- conversions ----------------
__global__ void xconv_kernel(const float* __restrict__ x, u16* __restrict__ o, int n4)
{
    int i = blockIdx.x * blockDim.x + threadIdx.x;
    if (i >= n4) return;
    float4 v = ((const float4*)x)[i];
    ushort4 u;
    u.x = f2bf(v.x); u.y = f2bf(v.y); u.z = f2bf(v.z); u.w = f2bf(v.w);
    ((ushort4*)o)[i] = u;
}

__global__ void wconv_kernel(const float* __restrict__ W, u16* __restrict__ WT,
                             int K, int M, int count)
{
    int idx = blockIdx.x * blockDim.x + threadIdx.x;
    int per = K * M;
    if (idx >= per * count) return;
    int b = idx / per, rem = idx - b * per;
    int k = rem / M, m = rem - k * M;
    WT[(size_t)b * per + (size_t)m * K + k] = f2bf(W[idx]);
}

__global__ void wsum_kernel(const float* __restrict__ Wself, u16* __restrict__ WT)
{
    int idx = blockIdx.x * blockDim.x + threadIdx.x;
    const int per = H_DIM * H_DIM;
    if (idx >= 2 * per) return;
    int l = idx / per, rem = idx - l * per;
    int k = rem / H_DIM, m = rem - k * H_DIM;
    float v = Wself[(size_t)(l * 3 + 0) * per + rem] + Wself[(size_t)(l * 3 + 1) * per + rem];
    WT[(size_t)l * per + (size_t)m * H_DIM + k] = f2bf(v);
}

__global__ void bsum_kernel(const float* __restrict__ bconv, float* __restrict__ bsum)
{
    int idx = blockIdx.x * blockDim.x + threadIdx.x;
    if (idx >= 2 * H_DIM) return;
    int l = idx >> 8, j = idx & 255;
    bsum[idx] = bconv[(l * 3 + 0) * H_DIM + j] + bconv[(l * 3 + 1) * H_DIM + j];
}

// ---------------- CSR build ----------------
__global__ void degi_kernel(const int* __restrict__ dst, int* __restrict__ deg, int E)
{
    int i = blockIdx.x * blockDim.x + threadIdx.x;
    if (i < E) atomicAdd(&deg[dst[i]], 1);
}

__device__ __forceinline__ int block_exscan256(int val, int* lds, int* total)
{
    int t = threadIdx.x;
    lds[t] = val;
    __syncthreads();
    #pragma unroll
    for (int off = 1; off < 256; off <<= 1) {
        int y = (t >= off) ? lds[t - off] : 0;
        __syncthreads();
        lds[t] += y;
        __syncthreads();
    }
    int inc = lds[t];
    *total = lds[255];
    __syncthreads();
    return inc - val;
}

__global__ void scan1_kernel(const int* __restrict__ in, int* __restrict__ out,
                             int* __restrict__ sums, int n)
{
    __shared__ int lds[256];
    int t = threadIdx.x;
    int base = blockIdx.x * 1024 + t * 4;
    int v0 = 0, v1 = 0, v2 = 0, v3 = 0;
    if (base + 3 < n) {
        int4 q = *(const int4*)(in + base);
        v0 = q.x; v1 = q.y; v2 = q.z; v3 = q.w;
    } else {
        if (base     < n) v0 = in[base];
        if (base + 1 < n) v1 = in[base + 1];
        if (base + 2 < n) v2 = in[base + 2];
    }
    int tot = v0 + v1 + v2 + v3, bt;
    int ex = block_exscan256(tot, lds, &bt);
    if (base     < n) out[base]     = ex;
    if (base + 1 < n) out[base + 1] = ex + v0;
    if (base + 2 < n) out[base + 2] = ex + v0 + v1;
    if (base + 3 < n) out[base + 3] = ex + v0 + v1 + v2;
    if (t == 0) sums[blockIdx.x] = bt;
}

__global__ void scan2_kernel(int* __restrict__ sums, int nc)
{
    __shared__ int lds[256];
    int t = threadIdx.x;
    int v = (t < nc) ? sums[t] : 0;
    int bt;
    int ex = block_exscan256(v, lds, &bt);
    if (t < nc) sums[t] = ex;
}

__global__ void scan3_kernel(int* __restrict__ cur, const int* __restrict__ sums, int n)
{
    int i = blockIdx.x * blockDim.x + threadIdx.x;
    if (i < n) cur[i] += sums[i >> 10];
}

__global__ void csr_fill_kernel(const int* __restrict__ src, const int* __restrict__ dst,
                                int* __restrict__ cur, int* __restrict__ csr, int E)
{
    int e = blockIdx.x * blockDim.x + threadIdx.x;
    if (e < E) {
        int pos = atomicAdd(&cur[dst[e]], 1);
        csr[pos] = src[e];
    }
}

// ---------------- pull-style mean aggregation: 2 dst rows per wave, 16 B/lane ----------------
typedef unsigned short u16x8 __attribute__((ext_vector_type(8)));

__launch_bounds__(256)
__global__ void gather_mean_kernel(const u16* __restrict__ h, const int* __restrict__ cur,
                                   const int* __restrict__ deg, const int* __restrict__ csr,
                                   u16* __restrict__ agg, int N)
{
    int gid = blockIdx.x * blockDim.x + threadIdx.x;
    int d = gid >> 5;
    if (d >= N) return;
    int l = gid & 31;               // 32 chunks of 8 bf16 per 256-wide row
    int dg = deg[d];
    int o  = cur[d] - dg;
    float a[8] = {};
    for (int i = 0; i < dg; ++i) {
        int s = csr[o + i];
        u16x8 v = *(const u16x8*)(h + (size_t)s * H_DIM + l * 8);
        #pragma unroll
        for (int t = 0; t < 8; ++t) a[t] += bf2f(v[t]);
    }
    float r = (dg > 0) ? (1.0f / (float)dg) : 0.f;
    u16x8 u;
    #pragma unroll
    for (int t = 0; t < 8; ++t) u[t] = f2bf(a[t] * r);
    *(u16x8*)(agg + (size_t)d * H_DIM + l * 8) = u;
}

// ---------------- in-place log_softmax ----------------
__launch_bounds__(256)
__global__ void logsoftmax_kernel(float* __restrict__ x, int N, int C)
{
    int gid = blockIdx.x * blockDim.x + threadIdx.x;
    int row = gid >> 6;
    if (row >= N) return;
    int lane = threadIdx.x & 63;
    float v = (lane < C) ? x[(size_t)row * C + lane] : -3.0e38f;
    float m = v;
    #pragma unroll
    for (int off = 32; off; off >>= 1) m = fmaxf(m, __shfl_xor(m, off, 64));
    float e = (lane < C) ? __expf(v - m) : 0.f;
    float s = e;
    #pragma unroll
    for (int off = 32; off; off >>= 1) s += __shfl_xor(s, off, 64);
    float ls = logf(s);
    if (lane < C) x[(size_t)row * C + lane] = v - m - ls;
}

// ======================================================================================
extern "C" void kernel_launch(void* const* d_in, const int* in_sizes, int n_in,
                              void* d_out, int out_size, void* d_ws, size_t ws_size,
                              hipStream_t stream)
{
    const float* x_author = (const float*)d_in[0];
    const float* x_paper  = (const float*)d_in[1];
    const int* e0s = (const int*)d_in[2]; const int* e0d = (const int*)d_in[3];
    const int* e1s = (const int*)d_in[4]; const int* e1d = (const int*)d_in[5];
    const int* e2s = (const int*)d_in[6]; const int* e2d = (const int*)d_in[7];
    const float* embWa = (const float*)d_in[8];  const float* embba = (const float*)d_in[9];
    const float* embWp = (const float*)d_in[10]; const float* embbp = (const float*)d_in[11];
    const float* Wself  = (const float*)d_in[12];
    const float* Wneigh = (const float*)d_in[13];
    const float* bconv  = (const float*)d_in[14];
    const float* lnga = (const float*)d_in[15]; const float* lnba = (const float*)d_in[16];
    const float* lngp = (const float*)d_in[17]; const float* lnbp = (const float*)d_in[18];
    const float* pW1a = (const float*)d_in[19]; const float* pb1a = (const float*)d_in[20];
    const float* pW2a = (const float*)d_in[21]; const float* pb2a = (const float*)d_in[22];
    const float* pW1p = (const float*)d_in[23]; const float* pb1p = (const float*)d_in[24];
    const float* pW2p = (const float*)d_in[25];

    // ---- workspace carve ----
    char* wp = (char*)d_ws;
    auto carveF = [&](size_t n) { float* p = (float*)wp; wp += n * sizeof(float); return p; };
    auto carveU = [&](size_t n) { u16* p = (u16*)wp; wp += n * sizeof(u16); return p; };
    auto carveI = [&](size_t n) { int* p = (int*)wp; wp += n * sizeof(int); return p; };

    float* BSUM = carveF(2 * H_DIM);

    u16* HA16  = carveU((size_t)A_N * H_DIM);
    u16* HP16  = carveU((size_t)P_N * H_DIM);
    u16* AGG0  = carveU((size_t)P_N * H_DIM);
    u16* AGG1  = carveU((size_t)P_N * H_DIM);
    u16* AGGA  = carveU((size_t)A_N * H_DIM);
    u16* XA16  = carveU((size_t)A_N * DIN);
    u16* XP16  = carveU((size_t)P_N * DIN);
    u16* WsT    = carveU(6 * H_DIM * H_DIM);
    u16* WnT    = carveU(6 * H_DIM * H_DIM);
    u16* WsumT  = carveU(2 * H_DIM * H_DIM);
    u16* embWaT = carveU(DIN * H_DIM);
    u16* embWpT = carveU(DIN * H_DIM);
    u16* pW1aT  = carveU(H_DIM * H_DIM);
    u16* pW2aT  = carveU(H_DIM * C_CLS);
    u16* pW1pT  = carveU(H_DIM * H_DIM);
    u16* pW2pT  = carveU(H_DIM * H_DIM);

    int* ideg = carveI(2 * P_N + A_N);
    int* icur = carveI(2 * P_N + A_N);
    int* icsr = carveI(3 * E_N);
    int* isum = carveI(3 * 256);

    int* deg0 = ideg; int* deg1 = deg0 + P_N; int* deg2 = deg1 + P_N;
    int* cur0 = icur; int* cur1 = cur0 + P_N; int* cur2 = cur1 + P_N;
    int* csr0 = icsr; int* csr1 = csr0 + E_N; int* csr2 = csr1 + E_N;
    int* sum0 = isum; int* sum1 = sum0 + 256; int* sum2 = sum1 + 256;

    float* oaOut = (float*)d_out;                  // A_N * C_CLS
    float* opOut = oaOut + (size_t)A_N * C_CLS;    // P_N * H_DIM

    auto gemm = [&](const u16* a0, const u16* b0, const u16* a1, const u16* b1,
                    const u16* a2, const u16* b2, int nseg, const float* bias,
                    float* c32, u16* c16, int N, int K, int M, int relu) {
        dim3 grid((M + GBM - 1) / GBM, (N + GBN - 1) / GBN);
        gemm_mfma2<<<grid, 256, 0, stream>>>(a0, a1, a2, b0, b1, b2, nseg, bias, c32, c16, N, K, M, relu);
    };

    // ---- weight / input conversions ----
    xconv_kernel<<<((A_N * DIN / 4) + 255) / 256, 256, 0, stream>>>(x_author, XA16, A_N * DIN / 4);
    xconv_kernel<<<((P_N * DIN / 4) + 255) / 256, 256, 0, stream>>>(x_paper,  XP16, P_N * DIN / 4);
    wconv_kernel<<<(DIN * H_DIM + 255) / 256, 256, 0, stream>>>(embWa, embWaT, DIN, H_DIM, 1);
    wconv_kernel<<<(DIN * H_DIM + 255) / 256, 256, 0, stream>>>(embWp, embWpT, DIN, H_DIM, 1);
    wconv_kernel<<<(6 * H_DIM * H_DIM + 255) / 256, 256, 0, stream>>>(Wself,  WsT, H_DIM, H_DIM, 6);
    wconv_kernel<<<(6 * H_DIM * H_DIM + 255) / 256, 256, 0, stream>>>(Wneigh, WnT, H_DIM, H_DIM, 6);
    wsum_kernel<<<(2 * H_DIM * H_DIM + 255) / 256, 256, 0, stream>>>(Wself, WsumT);
    bsum_kernel<<<2, 256, 0, stream>>>(bconv, BSUM);
    wconv_kernel<<<(H_DIM * H_DIM + 255) / 256, 256, 0, stream>>>(pW1a, pW1aT, H_DIM, H_DIM, 1);
    wconv_kernel<<<(H_DIM * C_CLS + 255) / 256, 256, 0, stream>>>(pW2a, pW2aT, H_DIM, C_CLS, 1);
    wconv_kernel<<<(H_DIM * H_DIM + 255) / 256, 256, 0, stream>>>(pW1p, pW1pT, H_DIM, H_DIM, 1);
    wconv_kernel<<<(H_DIM * H_DIM + 255) / 256, 256, 0, stream>>>(pW2p, pW2pT, H_DIM, H_DIM, 1);

    // ---- CSR build ----
    hipMemsetAsync(ideg, 0, (size_t)(2 * P_N + A_N) * sizeof(int), stream);
    const int eB = (E_N + 255) / 256;
    degi_kernel<<<eB, 256, 0, stream>>>(e0d, deg0, E_N);
    degi_kernel<<<eB, 256, 0, stream>>>(e1d, deg1, E_N);
    degi_kernel<<<eB, 256, 0, stream>>>(e2d, deg2, E_N);

    auto build_scan = [&](int* deg, int* cur, int* sums, int n) {
        int nc = (n + 1023) / 1024;
        scan1_kernel<<<nc, 256, 0, stream>>>(deg, cur, sums, n);
        scan2_kernel<<<1, 256, 0, stream>>>(sums, nc);
        scan3_kernel<<<(n + 255) / 256, 256, 0, stream>>>(cur, sums, n);
    };
    build_scan(deg0, cur0, sum0, P_N);
    build_scan(deg1, cur1, sum1, P_N);
    build_scan(deg2, cur2, sum2, A_N);

    csr_fill_kernel<<<eB, 256, 0, stream>>>(e0s, e0d, cur0, csr0, E_N);
    csr_fill_kernel<<<eB, 256, 0, stream>>>(e1s, e1d, cur1, csr1, E_N);
    csr_fill_kernel<<<eB, 256, 0, stream>>>(e2s, e2d, cur2, csr2, E_N);

    // ---- input embeddings (bf16 out) ----
    gemm(XA16, embWaT, 0, 0, 0, 0, 1, embba, nullptr, HA16, A_N, DIN, H_DIM, 0);
    gemm(XP16, embWpT, 0, 0, 0, 0, 1, embbp, nullptr, HP16, P_N, DIN, H_DIM, 0);

    const int gaBlkP = (P_N * 32 + 255) / 256;
    const int gaBlkA = (A_N * 32 + 255) / 256;
    const size_t W2 = (size_t)H_DIM * H_DIM;

    for (int l = 0; l < 2; ++l) {
        // aggregations (read pre-update H)
        gather_mean_kernel<<<gaBlkP, 256, 0, stream>>>(HA16, cur0, deg0, csr0, AGG0, P_N);
        gather_mean_kernel<<<gaBlkP, 256, 0, stream>>>(HP16, cur1, deg1, csr1, AGG1, P_N);
        gather_mean_kernel<<<gaBlkA, 256, 0, stream>>>(HP16, cur2, deg2, csr2, AGGA, A_N);

        // paper: hp@(Ws0+Ws1) + agg0@Wn0 + agg1@Wn1 + (b0+b1), then relu+residual+LN in-place
        gemm_ln<<<(P_N + 63) / 64, 256, 0, stream>>>(
            HP16, AGG0, AGG1,
            WsumT + (size_t)l * W2, WnT + (size_t)(l * 3 + 0) * W2, WnT + (size_t)(l * 3 + 1) * W2,
            3, BSUM + l * H_DIM, lngp, lnbp, HP16, P_N);

        // author: ha@Ws2 + aggA@Wn2 + b2, then relu+residual+LN in-place
        gemm_ln<<<(A_N + 63) / 64, 256, 0, stream>>>(
            HA16, AGGA, (const u16*)nullptr,
            WsT + (size_t)(l * 3 + 2) * W2, WnT + (size_t)(l * 3 + 2) * W2, (const u16*)nullptr,
            2, bconv + (size_t)(l * 3 + 2) * H_DIM, lnga, lnba, HA16, A_N);
    }

    // ---- output heads ----
    u16* TMPA16 = AGGA;   // free after layers
    u16* TMPP16 = AGG0;
    gemm(HA16, pW1aT, 0, 0, 0, 0, 1, pb1a, nullptr, TMPA16, A_N, H_DIM, H_DIM, 1);
    gemm(TMPA16, pW2aT, 0, 0, 0, 0, 1, pb2a, oaOut, nullptr, A_N, H_DIM, C_CLS, 0);
    logsoftmax_kernel<<<(A_N * 64 + 255) / 256, 256, 0, stream>>>(oaOut, A_N, C_CLS);

    gemm(HP16, pW1pT, 0, 0, 0, 0, 1, pb1p, nullptr, TMPP16, P_N, H_DIM, H_DIM, 1);
    gemm(TMPP16, pW2pT, 0, 0, 0, 0, 1, nullptr, opOut, nullptr, P_N, H_DIM, H_DIM, 0);
}